// Round 1
// baseline (1679.246 us; speedup 1.0000x reference)
//
#include <hip/hip_runtime.h>
#include <math.h>

#define NB 4
#define SL 4096
#define DIMQ 7168
#define NH 128
#define DK 128
#define DC 512
#define DCQ 1536
#define NR 64

// ws layout (float offsets)
#define OFF_KV      0u          // NB*SL*DC            = 8388608  (33.5 MB)
#define OFF_QHK     8388608u    // NB*NH*DK            = 65536
#define OFF_QBIG    8454144u    // NB*NH*DCQ           = 786432
#define OFF_QR      9240576u    // NB*NH*NR            = 32768   (zeroed, atomic target)
#define OFF_CTXC    9273344u    // NB*NH*DC            = 262144  (zeroed, atomic target)
#define OFF_QK      9535488u    // NB*NH*DC            = 262144
#define OFF_SC      9797632u    // NB*NH*SL            = 2097152 (scores; softmax in-place)
#define OFF_CTXLAT  11894784u   // NB*NH*DK            = 65536
#define ZERO_N      294912      // q_r + ctx_c contiguous

// ---------------- zero the atomic-accumulation targets + d_out ----------------
__global__ __launch_bounds__(256) void k_zero(float* __restrict__ zws, float* __restrict__ out) {
    int i = blockIdx.x * 256 + threadIdx.x;
    if (i < ZERO_N) zws[i] = 0.0f;
    if (i < NB * DIMQ) out[i] = 0.0f;
}

// ---------------- RoPE on kv_c -> kv ----------------
__global__ __launch_bounds__(256) void k_rope(const float* __restrict__ kv_c, float* __restrict__ kv) {
    int bl = blockIdx.x;
    int l = bl & (SL - 1);
    int t = threadIdx.x;  // freq index 0..255
    const float* x = kv_c + (size_t)bl * DC;
    float* y = kv + (size_t)bl * DC;
    float inv = powf(10000.0f, -(float)t * (1.0f / 256.0f));
    float ang = (float)l * inv;
    float s, c;
    sincosf(ang, &s, &c);
    float x0 = x[2 * t], x1 = x[2 * t + 1];
    float r0, r1;
    if (t < 128) { r0 = -x[2 * t + 256]; r1 = -x[2 * t + 257]; }
    else         { r0 =  x[2 * t - 256]; r1 =  x[2 * t - 255]; }
    y[2 * t]     = x0 * c + r0 * s;
    y[2 * t + 1] = x1 * c + r1 * s;
}

// ---------------- q_hk[b,n] = dot(hidden_q[b,:], Wq[n,:]) ----------------
__global__ __launch_bounds__(256) void k_qhk(const float* __restrict__ hq, const float* __restrict__ Wq,
                                             float* __restrict__ q_hk) {
    int t = threadIdx.x;
    int n = blockIdx.x * 64 + (t >> 2);
    int p = t & 3;
    const float4* wrow = (const float4*)(Wq + (size_t)n * DIMQ);
    const float4* h0p = (const float4*)(hq);
    const float4* h1p = (const float4*)(hq + DIMQ);
    const float4* h2p = (const float4*)(hq + 2 * DIMQ);
    const float4* h3p = (const float4*)(hq + 3 * DIMQ);
    float a0 = 0, a1 = 0, a2 = 0, a3 = 0;
    for (int j = 0; j < DIMQ / 16; ++j) {
        int i4 = j * 4 + p;
        float4 w = wrow[i4];
        float4 v;
        v = h0p[i4]; a0 += w.x * v.x + w.y * v.y + w.z * v.z + w.w * v.w;
        v = h1p[i4]; a1 += w.x * v.x + w.y * v.y + w.z * v.z + w.w * v.w;
        v = h2p[i4]; a2 += w.x * v.x + w.y * v.y + w.z * v.z + w.w * v.w;
        v = h3p[i4]; a3 += w.x * v.x + w.y * v.y + w.z * v.z + w.w * v.w;
    }
    a0 += __shfl_down(a0, 2); a0 += __shfl_down(a0, 1);
    a1 += __shfl_down(a1, 2); a1 += __shfl_down(a1, 1);
    a2 += __shfl_down(a2, 2); a2 += __shfl_down(a2, 1);
    a3 += __shfl_down(a3, 2); a3 += __shfl_down(a3, 1);
    if (p == 0) {
        q_hk[0 * (NH * DK) + n] = a0;
        q_hk[1 * (NH * DK) + n] = a1;
        q_hk[2 * (NH * DK) + n] = a2;
        q_hk[3 * (NH * DK) + n] = a3;
    }
}

// ---------------- q_big[b,h,q] = sum_k q_hk[b,h,k] * w_kc_q[h,k,q] ----------------
__global__ __launch_bounds__(256) void k_qbig(const float* __restrict__ q_hk, const float* __restrict__ w_kc_q,
                                              float* __restrict__ q_big) {
    int h = blockIdx.x / 6;
    int qc = blockIdx.x % 6;
    int q = qc * 256 + threadIdx.x;
    const float* w = w_kc_q + (size_t)h * DK * DCQ + q;
    const float* qh = q_hk + h * DK;
    float a0 = 0, a1 = 0, a2 = 0, a3 = 0;
    for (int k = 0; k < DK; ++k) {
        float wv = w[(size_t)k * DCQ];
        a0 += qh[k] * wv;
        a1 += qh[NH * DK + k] * wv;
        a2 += qh[2 * NH * DK + k] * wv;
        a3 += qh[3 * NH * DK + k] * wv;
    }
    q_big[((size_t)(0 * NH + h)) * DCQ + q] = a0;
    q_big[((size_t)(1 * NH + h)) * DCQ + q] = a1;
    q_big[((size_t)(2 * NH + h)) * DCQ + q] = a2;
    q_big[((size_t)(3 * NH + h)) * DCQ + q] = a3;
}

// ---------------- q_r[b,h,r] = sum_q q_big[b,h,q] * W_qr[h,q,r] ----------------
__global__ __launch_bounds__(256) void k_qr(const float* __restrict__ q_big, const float* __restrict__ W_qr,
                                            float* __restrict__ q_r) {
    int h = blockIdx.x >> 1;
    int qhalf = blockIdx.x & 1;
    int t = threadIdx.x;
    int b = t >> 6;
    int r = t & 63;
    const float* w = W_qr + (size_t)h * DCQ * NR + r;
    const float* qb = q_big + ((size_t)b * NH + h) * DCQ;
    float acc = 0;
    int q0 = qhalf * (DCQ / 2);
    for (int q = q0; q < q0 + DCQ / 2; ++q)
        acc += qb[q] * w[(size_t)q * NR];
    atomicAdd(q_r + ((size_t)(b * NH + h)) * NR + r, acc);
}

// ---------------- qk[b,h,d] = sum_r q_r[b,h,r] * W_kr[h,d,r] ----------------
__global__ __launch_bounds__(256) void k_qk(const float* __restrict__ q_r, const float* __restrict__ W_kr,
                                            float* __restrict__ qk) {
    int h = blockIdx.x;
    int t = threadIdx.x;
    const float4* w0 = (const float4*)(W_kr + (size_t)h * DC * NR + (size_t)t * NR);
    const float4* w1 = (const float4*)(W_kr + (size_t)h * DC * NR + (size_t)(t + 256) * NR);
    const float4* qr4 = (const float4*)q_r;
    float acc0[NB] = {0, 0, 0, 0};
    float acc1[NB] = {0, 0, 0, 0};
#pragma unroll
    for (int r4 = 0; r4 < NR / 4; ++r4) {
        float4 a = w0[r4];
        float4 c = w1[r4];
#pragma unroll
        for (int b = 0; b < NB; ++b) {
            float4 qv = qr4[(size_t)(b * NH + h) * (NR / 4) + r4];
            acc0[b] += a.x * qv.x + a.y * qv.y + a.z * qv.z + a.w * qv.w;
            acc1[b] += c.x * qv.x + c.y * qv.y + c.z * qv.z + c.w * qv.w;
        }
    }
#pragma unroll
    for (int b = 0; b < NB; ++b) {
        qk[((size_t)(b * NH + h)) * DC + t] = acc0[b];
        qk[((size_t)(b * NH + h)) * DC + t + 256] = acc1[b];
    }
}

// ---------------- scores[b,h,l] = sum_d kv[b,l,d] * qk[b,h,d] ----------------
__global__ __launch_bounds__(256) void k_scores(const float* __restrict__ kv, const float* __restrict__ qk,
                                                float* __restrict__ scores) {
    int b = blockIdx.x >> 7;
    int lc = blockIdx.x & 127;
    int t = threadIdx.x;
    int ll = t >> 3;
    int dg = t & 7;
    int l = lc * 32 + ll;
    const float4* kvrow = (const float4*)(kv + ((size_t)b * SL + l) * DC + dg * 64);
    float4 kr[16];
#pragma unroll
    for (int j = 0; j < 16; ++j) kr[j] = kvrow[j];
    for (int h = 0; h < NH; ++h) {
        const float4* q4 = (const float4*)(qk + ((size_t)(b * NH + h)) * DC + dg * 64);
        float p = 0;
#pragma unroll
        for (int j = 0; j < 16; ++j) {
            float4 qv = q4[j];
            p += kr[j].x * qv.x + kr[j].y * qv.y + kr[j].z * qv.z + kr[j].w * qv.w;
        }
        p += __shfl_down(p, 4);
        p += __shfl_down(p, 2);
        p += __shfl_down(p, 1);
        if (dg == 0) scores[((size_t)(b * NH + h)) * SL + l] = p;
    }
}

// ---------------- softmax over l, in-place ----------------
__global__ __launch_bounds__(256) void k_softmax(float* __restrict__ sc) {
    int bh = blockIdx.x;
    int t = threadIdx.x;
    float4* row = (float4*)(sc + (size_t)bh * SL);
    float4 v[4];
    float m = -1e30f;
#pragma unroll
    for (int i = 0; i < 4; ++i) {
        v[i] = row[t + 256 * i];
        m = fmaxf(m, fmaxf(fmaxf(v[i].x, v[i].y), fmaxf(v[i].z, v[i].w)));
    }
    __shared__ float red[8];
#pragma unroll
    for (int off = 32; off; off >>= 1) m = fmaxf(m, __shfl_xor(m, off));
    int wid = t >> 6, lane = t & 63;
    if (lane == 0) red[wid] = m;
    __syncthreads();
    m = fmaxf(fmaxf(red[0], red[1]), fmaxf(red[2], red[3]));
    float s = 0;
#pragma unroll
    for (int i = 0; i < 4; ++i) {
        v[i].x = expf(v[i].x - m); v[i].y = expf(v[i].y - m);
        v[i].z = expf(v[i].z - m); v[i].w = expf(v[i].w - m);
        s += v[i].x + v[i].y + v[i].z + v[i].w;
    }
#pragma unroll
    for (int off = 32; off; off >>= 1) s += __shfl_xor(s, off);
    if (lane == 0) red[4 + wid] = s;
    __syncthreads();
    float inv = 1.0f / (red[4] + red[5] + red[6] + red[7]);
#pragma unroll
    for (int i = 0; i < 4; ++i) {
        v[i].x *= inv; v[i].y *= inv; v[i].z *= inv; v[i].w *= inv;
        row[t + 256 * i] = v[i];
    }
}

// ---------------- ctx_c[b,h,d] += sum_l attn[b,h,l] * kv[b,l,d] ----------------
__global__ __launch_bounds__(256) void k_ctx(const float* __restrict__ attn, const float* __restrict__ kv,
                                             float* __restrict__ ctx_c) {
    int bid = blockIdx.x;
    int b = bid >> 6;
    int ht = (bid >> 3) & 7;
    int lc = bid & 7;
    int t = threadIdx.x;
    int h0 = ht * 16, l0 = lc * 512;
    float acc[16][2];
#pragma unroll
    for (int hh = 0; hh < 16; ++hh) { acc[hh][0] = 0; acc[hh][1] = 0; }
    const float* kvb = kv + ((size_t)b * SL + l0) * DC;
    const float* ab = attn + ((size_t)(b * NH + h0)) * SL + l0;
    for (int l = 0; l < 512; ++l) {
        float kv0 = kvb[(size_t)l * DC + t];
        float kv1 = kvb[(size_t)l * DC + t + 256];
#pragma unroll
        for (int hh = 0; hh < 16; ++hh) {
            float a = ab[(size_t)hh * SL + l];  // block-uniform -> scalar load
            acc[hh][0] += a * kv0;
            acc[hh][1] += a * kv1;
        }
    }
#pragma unroll
    for (int hh = 0; hh < 16; ++hh) {
        atomicAdd(ctx_c + ((size_t)(b * NH + h0 + hh)) * DC + t, acc[hh][0]);
        atomicAdd(ctx_c + ((size_t)(b * NH + h0 + hh)) * DC + t + 256, acc[hh][1]);
    }
}

// ---------------- ctx_lat[b,h,k] = sum_d ctx_c[b,h,d] * w_kc_kv[h,k,d] ----------------
__global__ __launch_bounds__(256) void k_ctxlat(const float* __restrict__ ctx_c, const float* __restrict__ w_kc_kv,
                                                float* __restrict__ ctx_lat) {
    int h = blockIdx.x >> 4;
    int kt = blockIdx.x & 15;
    int t = threadIdx.x;
    int kk = kt * 8 + (t >> 5);
    int dg = t & 31;
    const float4* w4 = (const float4*)(w_kc_kv + ((size_t)h * DK + kk) * DC) + dg * 4;
    float a[NB] = {0, 0, 0, 0};
#pragma unroll
    for (int i = 0; i < 4; ++i) {
        float4 w = w4[i];
#pragma unroll
        for (int b = 0; b < NB; ++b) {
            float4 c = ((const float4*)(ctx_c + ((size_t)(b * NH + h)) * DC))[dg * 4 + i];
            a[b] += w.x * c.x + w.y * c.y + w.z * c.z + w.w * c.w;
        }
    }
#pragma unroll
    for (int b = 0; b < NB; ++b) {
#pragma unroll
        for (int off = 16; off; off >>= 1) a[b] += __shfl_down(a[b], off);
    }
    if (dg == 0) {
#pragma unroll
        for (int b = 0; b < NB; ++b)
            ctx_lat[(size_t)b * NH * DK + h * DK + kk] = a[b];
    }
}

// ---------------- out[b,m] = sum_n ctx_lat[b,n] * Wout[m,n] ----------------
__global__ __launch_bounds__(256) void k_out(const float* __restrict__ ctx_lat, const float* __restrict__ Wout,
                                             float* __restrict__ out) {
    int mt = blockIdx.x >> 2;
    int nq = blockIdx.x & 3;
    int t = threadIdx.x;
    int m = mt * 64 + (t >> 2);
    int p = t & 3;
    const float4* wrow = (const float4*)(Wout + (size_t)m * (NH * DK) + nq * 4096);
    const float4* c0 = (const float4*)(ctx_lat + 0 * NH * DK + nq * 4096);
    const float4* c1 = (const float4*)(ctx_lat + 1 * NH * DK + nq * 4096);
    const float4* c2 = (const float4*)(ctx_lat + 2 * NH * DK + nq * 4096);
    const float4* c3 = (const float4*)(ctx_lat + 3 * NH * DK + nq * 4096);
    float a0 = 0, a1 = 0, a2 = 0, a3 = 0;
    for (int j = 0; j < 256; ++j) {
        int i4 = j * 4 + p;
        float4 w = wrow[i4];
        float4 v;
        v = c0[i4]; a0 += w.x * v.x + w.y * v.y + w.z * v.z + w.w * v.w;
        v = c1[i4]; a1 += w.x * v.x + w.y * v.y + w.z * v.z + w.w * v.w;
        v = c2[i4]; a2 += w.x * v.x + w.y * v.y + w.z * v.z + w.w * v.w;
        v = c3[i4]; a3 += w.x * v.x + w.y * v.y + w.z * v.z + w.w * v.w;
    }
    a0 += __shfl_down(a0, 2); a0 += __shfl_down(a0, 1);
    a1 += __shfl_down(a1, 2); a1 += __shfl_down(a1, 1);
    a2 += __shfl_down(a2, 2); a2 += __shfl_down(a2, 1);
    a3 += __shfl_down(a3, 2); a3 += __shfl_down(a3, 1);
    if (p == 0) {
        atomicAdd(out + 0 * DIMQ + m, a0);
        atomicAdd(out + 1 * DIMQ + m, a1);
        atomicAdd(out + 2 * DIMQ + m, a2);
        atomicAdd(out + 3 * DIMQ + m, a3);
    }
}

extern "C" void kernel_launch(void* const* d_in, const int* in_sizes, int n_in,
                              void* d_out, int out_size, void* d_ws, size_t ws_size,
                              hipStream_t stream) {
    const float* hidden_q = (const float*)d_in[0];
    const float* kv_c     = (const float*)d_in[1];
    const float* Wq       = (const float*)d_in[2];
    const float* w_kc_q   = (const float*)d_in[3];
    const float* w_kc_kv  = (const float*)d_in[4];
    const float* W_qr     = (const float*)d_in[5];
    const float* W_kr     = (const float*)d_in[6];
    const float* Wout     = (const float*)d_in[7];
    float* out = (float*)d_out;
    float* ws = (float*)d_ws;

    float* kv      = ws + OFF_KV;
    float* q_hk    = ws + OFF_QHK;
    float* q_big   = ws + OFF_QBIG;
    float* q_r     = ws + OFF_QR;
    float* ctx_c   = ws + OFF_CTXC;
    float* qk      = ws + OFF_QK;
    float* sc      = ws + OFF_SC;
    float* ctxlat  = ws + OFF_CTXLAT;

    k_zero<<<(ZERO_N + 255) / 256, 256, 0, stream>>>(q_r, out);
    k_rope<<<NB * SL, 256, 0, stream>>>(kv_c, kv);
    k_qhk<<<(NH * DK) / 64, 256, 0, stream>>>(hidden_q, Wq, q_hk);
    k_qbig<<<NH * 6, 256, 0, stream>>>(q_hk, w_kc_q, q_big);
    k_qr<<<NH * 2, 256, 0, stream>>>(q_big, W_qr, q_r);
    k_qk<<<NH, 256, 0, stream>>>(q_r, W_kr, qk);
    k_scores<<<NB * 128, 256, 0, stream>>>(kv, qk, sc);
    k_softmax<<<NB * NH, 256, 0, stream>>>(sc);
    k_ctx<<<256, 256, 0, stream>>>(sc, kv, ctx_c);
    k_ctxlat<<<NH * 16, 256, 0, stream>>>(ctx_c, w_kc_kv, ctxlat);
    k_out<<<448, 256, 0, stream>>>(ctxlat, Wout, out);
}